// Round 4
// baseline (263.880 us; speedup 1.0000x reference)
//
#include <hip/hip_runtime.h>
#include <hip/hip_bf16.h>
#include <stdint.h>

// Problem constants (from reference)
#define T_DIM   4
#define N_GRID  12288
#define C_DIM   16
#define NH      9
#define N_OUT   1024        // UP*E
#define K_DIM   144         // NH*C
#define M_TOTAL 196608      // B*V*T*N_GRID
#define MG_ELEMS (8 * T_DIM * N_GRID * C_DIM)   // 6291456

#define AS_STRIDE 146       // f16 elems/row; 292B -> 73-word stride, odd => conflict-free b128
#define NTILES    4         // 64-row tiles per block (pipelined)
#define KSTEPS    9         // 144 / 16

typedef __attribute__((ext_vector_type(4)))  float    f32x4;
typedef __attribute__((ext_vector_type(16))) float    f32x16;
typedef __attribute__((ext_vector_type(4)))  _Float16 f16x4;
typedef __attribute__((ext_vector_type(8)))  _Float16 f16x8;

// ---------------------------------------------------------------------------
// Pre-pass 1: W (144x1024 f32) -> f16 packed in MFMA B-fragment order for
// v_mfma_f32_32x32x16_f16:
//   Wpk[((s*16+q)*64+lane)*16 + cg*8 + j] =
//     f16( W[(16*s + 8*(lane>>5) + j)*1024 + q*64 + cg*32 + (lane&31)] )
// ---------------------------------------------------------------------------
__global__ void pack_w_kernel(const float* __restrict__ W,
                              _Float16* __restrict__ Wpk) {
    const int gid  = blockIdx.x * blockDim.x + threadIdx.x;  // 0..18431
    const int cg   = gid & 1;
    const int lane = (gid >> 1) & 63;
    const int q    = (gid >> 7) & 15;
    const int s    = gid >> 11;          // 0..8
    const int l31  = lane & 31;
    const int lhi  = lane >> 5;

    _Float16 v[8];
#pragma unroll
    for (int j = 0; j < 8; ++j) {
        const int k   = 16 * s + 8 * lhi + j;             // 0..143
        const int col = q * 64 + cg * 32 + l31;           // 0..1023
        v[j] = (_Float16)W[k * N_OUT + col];
    }
    *(f16x8*)(Wpk + (size_t)gid * 8) = *(const f16x8*)v;
}

// ---------------------------------------------------------------------------
// Pre-pass 2: mg_emb f32 -> f16 (same layout). 25 MB -> 12.6 MB, L2-friendly.
// ---------------------------------------------------------------------------
__global__ void conv_mg_kernel(const float* __restrict__ mg,
                               _Float16* __restrict__ mgh) {
    const size_t n4 = MG_ELEMS / 4;
    const size_t stride = (size_t)gridDim.x * blockDim.x;
    for (size_t i = (size_t)blockIdx.x * blockDim.x + threadIdx.x; i < n4; i += stride) {
        f32x4 f = *(const f32x4*)(mg + 4 * i);
        f16x4 h;
#pragma unroll
        for (int j = 0; j < 4; ++j) h[j] = (_Float16)f[j];
        *(f16x4*)(mgh + 4 * i) = h;
    }
}

// ---------------------------------------------------------------------------
// Main kernel: pipelined multi-tile. Block = 512 threads (8 waves), covers
// 256 rows (4 tiles of 64) x 512 cols. Double-buffered LDS A-tiles; NT stores
// of tile t drain under tile t+1's MFMA phase -> near-continuous write stream.
// ---------------------------------------------------------------------------
__global__ __launch_bounds__(512, 4) void mg_gemm_kernel(
    const _Float16* __restrict__ mgh,   // (8, 4, 12288, 16) f16
    const int*   __restrict__ vidx,     // (1, 4)
    const int*   __restrict__ adjc,     // (12288, 9)
    const _Float16* __restrict__ Wpk,   // packed B fragments
    const float* __restrict__ bias,     // (1024,)
    float* __restrict__ out)            // (196608, 1024) f32
{
    __shared__ _Float16 As[2][64 * AS_STRIDE];   // 2 x 18688 B

    const int tid  = threadIdx.x;
    const int mblk = blockIdx.x;                 // 0..767
    const int R0   = mblk * (64 * NTILES);       // block base row (within one v,t: 256 | 12288)
    const int v    = R0 / (T_DIM * N_GRID);
    const int tt4  = (R0 / N_GRID) & 3;
    const int P0   = R0 % N_GRID;
    const int vi   = vidx[v];
    const _Float16* src = mgh + (size_t)(vi * T_DIM + tt4) * N_GRID * C_DIM;

    // gather task mapping: task = row*9+nh; thread does task=tid (+512 if tid<64)
    const int t0row = tid / NH, t0nh = tid - NH * t0row;
    const int tid2  = tid + 512;
    const int t1row = tid2 / NH, t1nh = tid2 - NH * t1row;
    const bool has2 = (tid < 64);

    const int lane = tid & 63;
    const int w    = tid >> 6;                   // wave 0..7
    const int l31  = lane & 31;
    const int lhi  = lane >> 5;
    const int q    = blockIdx.y * 8 + w;         // col-group 0..15

    const _Float16* wp = Wpk + ((size_t)q * 64 + lane) * 16;
    const int colbase  = q * 64 + l31;
    const float b0f = bias[colbase];
    const float b1f = bias[colbase + 32];

    f16x8 ha, hb, hc, hd;

    // ---- prologue: gather tile 0 into As[0] ----
    {
        int g0 = adjc[P0 * NH + tid];
        ha = *(const f16x8*)(src + (size_t)g0 * C_DIM);
        hb = *(const f16x8*)(src + (size_t)g0 * C_DIM + 8);
        if (has2) {
            int g1 = adjc[P0 * NH + tid2];
            hc = *(const f16x8*)(src + (size_t)g1 * C_DIM);
            hd = *(const f16x8*)(src + (size_t)g1 * C_DIM + 8);
        }
        _Float16* d0 = &As[0][t0row * AS_STRIDE + t0nh * C_DIM];
        *(f16x8*)d0 = ha; *(f16x8*)(d0 + 8) = hb;
        if (has2) {
            _Float16* d1 = &As[0][t1row * AS_STRIDE + t1nh * C_DIM];
            *(f16x8*)d1 = hc; *(f16x8*)(d1 + 8) = hd;
        }
    }
    __syncthreads();

    for (int t = 0; t < NTILES; ++t) {
        // ---- issue prefetch gather loads for tile t+1 (in flight over MFMA) ----
        if (t + 1 < NTILES) {
            const int p = P0 + 64 * (t + 1);
            int g0 = adjc[p * NH + tid];
            ha = *(const f16x8*)(src + (size_t)g0 * C_DIM);
            hb = *(const f16x8*)(src + (size_t)g0 * C_DIM + 8);
            if (has2) {
                int g1 = adjc[p * NH + tid2];
                hc = *(const f16x8*)(src + (size_t)g1 * C_DIM);
                hd = *(const f16x8*)(src + (size_t)g1 * C_DIM + 8);
            }
        }

        // ---- compute tile t from As[t&1] ----
        f32x16 acc00, acc01, acc10, acc11;
#pragma unroll
        for (int i = 0; i < 16; ++i) { acc00[i]=0.f; acc01[i]=0.f; acc10[i]=0.f; acc11[i]=0.f; }

        const _Float16* arow0 = &As[t & 1][l31 * AS_STRIDE + 8 * lhi];
        const _Float16* arow1 = arow0 + 32 * AS_STRIDE;
#pragma unroll
        for (int s = 0; s < KSTEPS; ++s) {
            f16x8 a0 = *(const f16x8*)(arow0 + s * C_DIM);
            f16x8 a1 = *(const f16x8*)(arow1 + s * C_DIM);
            const _Float16* bp = wp + (size_t)s * (16 * 64 * 16);
            f16x8 b0 = *(const f16x8*)(bp + 0);
            f16x8 b1 = *(const f16x8*)(bp + 8);
            acc00 = __builtin_amdgcn_mfma_f32_32x32x16_f16(a0, b0, acc00, 0, 0, 0);
            acc01 = __builtin_amdgcn_mfma_f32_32x32x16_f16(a1, b0, acc01, 0, 0, 0);
            acc10 = __builtin_amdgcn_mfma_f32_32x32x16_f16(a0, b1, acc10, 0, 0, 0);
            acc11 = __builtin_amdgcn_mfma_f32_32x32x16_f16(a1, b1, acc11, 0, 0, 0);
        }

        // ---- commit prefetched gather into the other LDS buffer ----
        if (t + 1 < NTILES) {
            _Float16* d0 = &As[(t + 1) & 1][t0row * AS_STRIDE + t0nh * C_DIM];
            *(f16x8*)d0 = ha; *(f16x8*)(d0 + 8) = hb;
            if (has2) {
                _Float16* d1 = &As[(t + 1) & 1][t1row * AS_STRIDE + t1nh * C_DIM];
                *(f16x8*)d1 = hc; *(f16x8*)(d1 + 8) = hd;
            }
        }
        __syncthreads();

        // ---- store tile t (NT, drains under next tile's compute) ----
        float* outp = out + (size_t)(R0 + 64 * t) * N_OUT;
#pragma unroll
        for (int r = 0; r < 16; ++r) {
            const int rr = (r & 3) + 8 * (r >> 2) + 4 * lhi;   // 0..31
            __builtin_nontemporal_store(acc00[r] + b0f, &outp[(size_t)rr * N_OUT + colbase]);
            __builtin_nontemporal_store(acc10[r] + b1f, &outp[(size_t)rr * N_OUT + colbase + 32]);
            __builtin_nontemporal_store(acc01[r] + b0f, &outp[(size_t)(rr + 32) * N_OUT + colbase]);
            __builtin_nontemporal_store(acc11[r] + b1f, &outp[(size_t)(rr + 32) * N_OUT + colbase + 32]);
        }
    }
}

// ---------------------------------------------------------------------------
extern "C" void kernel_launch(void* const* d_in, const int* in_sizes, int n_in,
                              void* d_out, int out_size, void* d_ws, size_t ws_size,
                              hipStream_t stream) {
    const float* mg   = (const float*)d_in[0];   // mg_emb
    const int*   vidx = (const int*)  d_in[1];   // var_indices
    const int*   adjc = (const int*)  d_in[2];   // adjc
    const float* W    = (const float*)d_in[3];   // W
    const float* bias = (const float*)d_in[4];   // b
    float*       out  = (float*)d_out;

    _Float16* Wpk = (_Float16*)d_ws;                         // 294912 B
    _Float16* mgh = (_Float16*)((char*)d_ws + (1 << 20));    // 12.6 MB

    pack_w_kernel<<<dim3(72), dim3(256), 0, stream>>>(W, Wpk);
    conv_mg_kernel<<<dim3(1024), dim3(256), 0, stream>>>(mg, mgh);

    // pipelined gather+GEMM: 256 rows x 512 cols per block
    mg_gemm_kernel<<<dim3(M_TOTAL / (64 * NTILES), 2), dim3(512), 0, stream>>>(
        mgh, vidx, adjc, Wpk, bias, out);
}

// Round 5
// 221.198 us; speedup vs baseline: 1.1930x; 1.1930x over previous
//
#include <hip/hip_runtime.h>
#include <hip/hip_bf16.h>
#include <stdint.h>

// Problem constants (from reference)
#define T_DIM   4
#define N_GRID  12288
#define C_DIM   16
#define NH      9
#define N_OUT   1024        // UP*E
#define K_DIM   144         // NH*C
#define M_TOTAL 196608      // B*V*T*N_GRID
#define MG_ELEMS (8 * T_DIM * N_GRID * C_DIM)   // 6291456

#define AS_STRIDE 146       // f16 elems/row (292B, odd-word stride)
#define KSTEPS    9         // 144 / 16

typedef __attribute__((ext_vector_type(4)))  float    f32x4;
typedef __attribute__((ext_vector_type(16))) float    f32x16;
typedef __attribute__((ext_vector_type(4)))  _Float16 f16x4;
typedef __attribute__((ext_vector_type(8)))  _Float16 f16x8;

// ---------------------------------------------------------------------------
// Pre-pass 1: W (144x1024 f32) -> f16 packed in MFMA B-fragment order for
// v_mfma_f32_32x32x16_f16 (layout verified by R1/R2 refcheck):
//   Wpk[((s*16+q)*64+lane)*16 + cg*8 + j] =
//     f16( W[(16*s + 8*(lane>>5) + j)*1024 + q*64 + cg*32 + (lane&31)] )
// ---------------------------------------------------------------------------
__global__ void pack_w_kernel(const float* __restrict__ W,
                              _Float16* __restrict__ Wpk) {
    const int gid  = blockIdx.x * blockDim.x + threadIdx.x;  // 0..18431
    const int cg   = gid & 1;
    const int lane = (gid >> 1) & 63;
    const int q    = (gid >> 7) & 15;
    const int s    = gid >> 11;          // 0..8
    const int l31  = lane & 31;
    const int lhi  = lane >> 5;

    _Float16 v[8];
#pragma unroll
    for (int j = 0; j < 8; ++j) {
        const int k   = 16 * s + 8 * lhi + j;             // 0..143
        const int col = q * 64 + cg * 32 + l31;           // 0..1023
        v[j] = (_Float16)W[k * N_OUT + col];
    }
    *(f16x8*)(Wpk + (size_t)gid * 8) = *(const f16x8*)v;
}

// ---------------------------------------------------------------------------
// Pre-pass 2: mg_emb f32 -> f16 (same layout). 25 MB -> 12.6 MB.
// ---------------------------------------------------------------------------
__global__ void conv_mg_kernel(const float* __restrict__ mg,
                               _Float16* __restrict__ mgh) {
    const size_t n4 = MG_ELEMS / 4;
    const size_t stride = (size_t)gridDim.x * blockDim.x;
    for (size_t i = (size_t)blockIdx.x * blockDim.x + threadIdx.x; i < n4; i += stride) {
        f32x4 f = *(const f32x4*)(mg + 4 * i);
        f16x4 h;
#pragma unroll
        for (int j = 0; j < 4; ++j) h[j] = (_Float16)f[j];
        *(f16x4*)(mgh + 4 * i) = h;
    }
}

// ---------------------------------------------------------------------------
// Main kernel (R2 structure + transpose epilogue).
// Block = 512 threads (8 waves), tile 64 rows x 512 cols, grid (3072, 2).
// Phases: gather A-tile -> LDS (f16) | MFMA | LDS-transpose epilogue with
// contiguous 1KB-per-instruction NT stores.
// ---------------------------------------------------------------------------
__global__ __launch_bounds__(512, 4) void mg_gemm_kernel(
    const _Float16* __restrict__ mgh,   // (8, 4, 12288, 16) f16
    const int*   __restrict__ vidx,     // (1, 4)
    const int*   __restrict__ adjc,     // (12288, 9)
    const _Float16* __restrict__ Wpk,   // packed B fragments
    const float* __restrict__ bias,     // (1024,)
    float* __restrict__ out)            // (196608, 1024) f32
{
    // 64 KB shared: A-tile (18.7 KB f16) during GEMM, then reused as the
    // 32x512 f32 transpose buffer in the epilogue.
    __shared__ __align__(16) char shmem_raw[65536];
    _Float16* As = (_Float16*)shmem_raw;
    float*    xp = (float*)shmem_raw;

    const int mtile = blockIdx.x;          // 0..3071
    const int ntile = blockIdx.y;          // 0..1
    const int r0    = mtile * 64;
    const int v     = r0 / (T_DIM * N_GRID);
    const int t     = (r0 / N_GRID) & 3;
    const int p0    = r0 % N_GRID;
    const int vi    = vidx[v];
    const _Float16* src = mgh + (size_t)(vi * T_DIM + t) * N_GRID * C_DIM;

    const int tid = threadIdx.x;

    // ---- stage A tile: 64 rows x 9 neighbors x 16 ch (f16, no cvt) ----
    for (int task = tid; task < 64 * NH; task += 512) {
        const int row = task / NH;
        const int nh  = task - row * NH;
        const int g   = adjc[p0 * NH + task];        // == adjc[(p0+row)*9 + nh]
        const _Float16* sp = src + (size_t)g * C_DIM;
        _Float16* dst = As + row * AS_STRIDE + nh * C_DIM;
        *(f16x8*)dst       = *(const f16x8*)sp;
        *(f16x8*)(dst + 8) = *(const f16x8*)(sp + 8);
    }
    __syncthreads();

    const int lane = tid & 63;
    const int w    = tid >> 6;             // wave 0..7
    const int l31  = lane & 31;
    const int lhi  = lane >> 5;
    const int q    = ntile * 8 + w;        // col-group 0..15

    f32x16 acc00, acc01, acc10, acc11;     // [colhalf][rowhalf]
#pragma unroll
    for (int i = 0; i < 16; ++i) { acc00[i]=0.f; acc01[i]=0.f; acc10[i]=0.f; acc11[i]=0.f; }

    const _Float16* arow0 = As + l31 * AS_STRIDE + 8 * lhi;
    const _Float16* arow1 = arow0 + 32 * AS_STRIDE;
    const _Float16* wp    = Wpk + ((size_t)q * 64 + lane) * 16;

#pragma unroll
    for (int s = 0; s < KSTEPS; ++s) {
        f16x8 a0 = *(const f16x8*)(arow0 + s * C_DIM);
        f16x8 a1 = *(const f16x8*)(arow1 + s * C_DIM);
        const _Float16* bp = wp + (size_t)s * (16 * 64 * 16);
        f16x8 b0 = *(const f16x8*)(bp + 0);
        f16x8 b1 = *(const f16x8*)(bp + 8);
        acc00 = __builtin_amdgcn_mfma_f32_32x32x16_f16(a0, b0, acc00, 0, 0, 0);
        acc01 = __builtin_amdgcn_mfma_f32_32x32x16_f16(a1, b0, acc01, 0, 0, 0);
        acc10 = __builtin_amdgcn_mfma_f32_32x32x16_f16(a0, b1, acc10, 0, 0, 0);
        acc11 = __builtin_amdgcn_mfma_f32_32x32x16_f16(a1, b1, acc11, 0, 0, 0);
    }

    // ---- epilogue: LDS transpose -> contiguous 1KB NT stores ----
    const int colbase = q * 64 + l31;
    const float b0f = bias[colbase];
    const float b1f = bias[colbase + 32];
    const int wcol = 64 * w + l31;
    float* outbase = out + (size_t)r0 * N_OUT + ntile * 512;
    const int rowb = 4 * w;                      // this wave's 4 rows per half

#pragma unroll
    for (int h = 0; h < 2; ++h) {
        // h=0: all waves' As reads complete; h=1: all half-0 xp reads complete
        __syncthreads();
#pragma unroll
        for (int r = 0; r < 16; ++r) {
            const int rr = (r & 3) + 8 * (r >> 2) + 4 * lhi;   // 0..31
            const float va = (h ? acc01[r] : acc00[r]) + b0f;
            const float vb = (h ? acc11[r] : acc10[r]) + b1f;
            xp[rr * 512 + wcol]      = va;
            xp[rr * 512 + wcol + 32] = vb;
        }
        __syncthreads();
#pragma unroll
        for (int a = 0; a < 4; ++a) {
#pragma unroll
            for (int j = 0; j < 2; ++j) {
                f32x4 vv = *(const f32x4*)&xp[(rowb + a) * 512 + 256 * j + 4 * lane];
                __builtin_nontemporal_store(vv,
                    (f32x4*)(outbase + (size_t)(32 * h + rowb + a) * N_OUT + 256 * j + 4 * lane));
            }
        }
    }
}

// ---------------------------------------------------------------------------
extern "C" void kernel_launch(void* const* d_in, const int* in_sizes, int n_in,
                              void* d_out, int out_size, void* d_ws, size_t ws_size,
                              hipStream_t stream) {
    const float* mg   = (const float*)d_in[0];   // mg_emb
    const int*   vidx = (const int*)  d_in[1];   // var_indices
    const int*   adjc = (const int*)  d_in[2];   // adjc
    const float* W    = (const float*)d_in[3];   // W
    const float* bias = (const float*)d_in[4];   // b
    float*       out  = (float*)d_out;

    _Float16* Wpk = (_Float16*)d_ws;                         // 294912 B
    _Float16* mgh = (_Float16*)((char*)d_ws + (1 << 20));    // 12.6 MB

    pack_w_kernel<<<dim3(72), dim3(256), 0, stream>>>(W, Wpk);
    conv_mg_kernel<<<dim3(1024), dim3(256), 0, stream>>>(mg, mgh);

    // gather+GEMM with transpose epilogue: 64x512 tiles
    mg_gemm_kernel<<<dim3(M_TOTAL / 64, 2), dim3(512), 0, stream>>>(
        mgh, vidx, adjc, Wpk, bias, out);
}